// Round 10
// baseline (244.080 us; speedup 1.0000x reference)
//
#include <hip/hip_runtime.h>
#include <hip/hip_bf16.h>

typedef float          f4  __attribute__((ext_vector_type(4)));
typedef unsigned short us4 __attribute__((ext_vector_type(4)));
typedef int            i2  __attribute__((ext_vector_type(2)));
typedef int            i4  __attribute__((ext_vector_type(4)));
typedef unsigned       u4  __attribute__((ext_vector_type(4)));

template <typename T>
__device__ __forceinline__ T ntload(const T* p) { return __builtin_nontemporal_load(p); }

__device__ __forceinline__ unsigned short f2bf(float f) {
    unsigned u = __float_as_uint(f);
    return (unsigned short)((u + 0x7FFF + ((u >> 16) & 1)) >> 16);   // RNE
}
__device__ __forceinline__ float bf2f(unsigned short h) {
    return __uint_as_float((unsigned)h << 16);
}

// ---- FAT kernel A: blocks [0,1024): degree histogram (2 edges/thread);
// [1024,1536): xw GEMM. deg: packed u32 = (count << 25) | fixed19(weight-sum);
// replica = (e>>8)&7 (pure function of e; must match k_bucket) ---------------
__global__ __launch_bounds__(256) void k_degxw(const int* __restrict__ ei,
                      const float* __restrict__ ew,
                      unsigned* __restrict__ deg_rep,
                      const float* __restrict__ x, const float* __restrict__ W1,
                      float* __restrict__ xw, unsigned short* __restrict__ xw16,
                      int N, int E) {
    __shared__ float w1l[128 * 64];   // 32 KB (xw branch)
    __shared__ f4    xt[16][32];      // 8 KB
    if (blockIdx.x < 1024) {
        int e0 = blockIdx.x * 512 + threadIdx.x;
        int e1 = e0 + 256;
        if (e0 < E) {
            int c = ntload(ei + E + e0);
            unsigned q = __float2uint_rn(ntload(ew + e0) * 524288.f);   // 2^19 fixed pt
            atomicAdd(&deg_rep[(size_t)((e0 >> 8) & 7) * N + c], (1u << 25) | q);
        }
        if (e1 < E) {
            int c = ntload(ei + E + e1);
            unsigned q = __float2uint_rn(ntload(ew + e1) * 524288.f);
            atomicAdd(&deg_rep[(size_t)((e1 >> 8) & 7) * N + c], (1u << 25) | q);
        }
        return;
    }
    int xbid = blockIdx.x - 1024;     // 512 xw blocks
    for (int t = threadIdx.x; t < 128 * 64; t += 256) w1l[t] = W1[t];
    int lane = threadIdx.x & 63;
    int wv   = threadIdx.x >> 6;
    for (int base = xbid * 16; base < N; base += 512 * 16) {
        __syncthreads();   // also covers w1l staging on first pass
        for (int t = threadIdx.x; t < 16 * 32; t += 256)
            ((f4*)xt)[t] = ntload((const f4*)x + (size_t)base * 32 + t);
        __syncthreads();
        int r0 = wv * 4;
        float a0 = 0.f, a1 = 0.f, a2 = 0.f, a3 = 0.f;
#pragma unroll
        for (int q = 0; q < 32; ++q) {
            f4 x0 = xt[r0][q], x1 = xt[r0 + 1][q], x2 = xt[r0 + 2][q], x3 = xt[r0 + 3][q];
            float wa = w1l[(4 * q + 0) * 64 + lane];
            float wb = w1l[(4 * q + 1) * 64 + lane];
            float wc = w1l[(4 * q + 2) * 64 + lane];
            float wd = w1l[(4 * q + 3) * 64 + lane];
            a0 = fmaf(x0.x, wa, a0); a0 = fmaf(x0.y, wb, a0); a0 = fmaf(x0.z, wc, a0); a0 = fmaf(x0.w, wd, a0);
            a1 = fmaf(x1.x, wa, a1); a1 = fmaf(x1.y, wb, a1); a1 = fmaf(x1.z, wc, a1); a1 = fmaf(x1.w, wd, a1);
            a2 = fmaf(x2.x, wa, a2); a2 = fmaf(x2.y, wb, a2); a2 = fmaf(x2.z, wc, a2); a2 = fmaf(x2.w, wd, a2);
            a3 = fmaf(x3.x, wa, a3); a3 = fmaf(x3.y, wb, a3); a3 = fmaf(x3.z, wc, a3); a3 = fmaf(x3.w, wd, a3);
        }
        int gr = base + r0;
        __builtin_nontemporal_store(a0, xw + (size_t)(gr + 0) * 64 + lane);
        __builtin_nontemporal_store(a1, xw + (size_t)(gr + 1) * 64 + lane);
        __builtin_nontemporal_store(a2, xw + (size_t)(gr + 2) * 64 + lane);
        __builtin_nontemporal_store(a3, xw + (size_t)(gr + 3) * 64 + lane);
        xw16[(size_t)(gr + 0) * 64 + lane] = f2bf(a0);
        xw16[(size_t)(gr + 1) * 64 + lane] = f2bf(a1);
        xw16[(size_t)(gr + 2) * 64 + lane] = f2bf(a2);
        xw16[(size_t)(gr + 3) * 64 + lane] = f2bf(a3);
    }
}

// ---- FUSED replica-reduce + prefix-scan (single 1024-thread block) ----------
// Per thread: 16 cols. Vectorized u32x4 reads of deg_rep, cursor_rep seeding
// (atomic in k_bucket then RETURNS base+arrival), cnt/dis writes, then the
// 2-barrier wave scan -> offs. Also zeroes ssg/cag/csg (4224 floats), so the
// host memset covers deg_rep only. Replaces k_red + k_scan (one launch saved).
__global__ __launch_bounds__(1024) void k_redscan(const unsigned* __restrict__ deg_rep,
                      int* __restrict__ cursor_rep, int* __restrict__ cnt,
                      float* __restrict__ dis, int* __restrict__ offs,
                      float* __restrict__ ssg, int N) {
    __shared__ int wsum[16];
    int tid = threadIdx.x;          // 1024 threads = 16 waves; N = 16384
    int lane = tid & 63, wv = tid >> 6;
    int base = tid * 16;
    for (int t = tid; t < 4224; t += 1024) ssg[t] = 0.f;   // ssg|cag|csg contiguous
    int cloc[16];
#pragma unroll
    for (int g = 0; g < 4; ++g) {
        int cb = base + 4 * g;
        unsigned r0 = 0, r1 = 0, r2 = 0, r3 = 0;
        unsigned w0 = 0, w1 = 0, w2 = 0, w3 = 0;
        const unsigned M = (1u << 25) - 1;
#pragma unroll
        for (int rep = 0; rep < 8; ++rep) {
            u4 p = *(const u4*)&deg_rep[(size_t)rep * N + cb];
            i4 seed; seed.x = (int)r0; seed.y = (int)r1; seed.z = (int)r2; seed.w = (int)r3;
            *(i4*)&cursor_rep[(size_t)rep * N + cb] = seed;
            r0 += p.x >> 25; r1 += p.y >> 25; r2 += p.z >> 25; r3 += p.w >> 25;
            w0 += p.x & M;   w1 += p.y & M;   w2 += p.z & M;   w3 += p.w & M;
        }
        cloc[4 * g + 0] = (int)r0; cloc[4 * g + 1] = (int)r1;
        cloc[4 * g + 2] = (int)r2; cloc[4 * g + 3] = (int)r3;
        i4 cv; cv.x = (int)r0; cv.y = (int)r1; cv.z = (int)r2; cv.w = (int)r3;
        *(i4*)&cnt[cb] = cv;
        f4 dv;
        dv.x = rsqrtf((float)w0 * (1.f / 524288.f) + 1.0f);
        dv.y = rsqrtf((float)w1 * (1.f / 524288.f) + 1.0f);
        dv.z = rsqrtf((float)w2 * (1.f / 524288.f) + 1.0f);
        dv.w = rsqrtf((float)w3 * (1.f / 524288.f) + 1.0f);
        *(f4*)&dis[cb] = dv;
    }
    // ---- exclusive scan over all 16384 counts ----
    int loc[16];
    int sum = 0;
#pragma unroll
    for (int i = 0; i < 16; ++i) { loc[i] = sum; sum += cloc[i]; }
    int s = sum;                    // inclusive scan over 64 lanes
#pragma unroll
    for (int o = 1; o < 64; o <<= 1) {
        int t = __shfl_up(s, o);
        if (lane >= o) s += t;
    }
    if (lane == 63) wsum[wv] = s;
    __syncthreads();
    if (wv == 0 && lane < 16) {     // scan the 16 wave totals
        int ws = wsum[lane];
        int ss = ws;
#pragma unroll
        for (int o = 1; o < 16; o <<= 1) {
            int t = __shfl_up(ss, o);
            if (lane >= o) ss += t;
        }
        wsum[lane] = ss - ws;       // exclusive prefix of wave sums
    }
    __syncthreads();
    int excl = s - sum + wsum[wv];
#pragma unroll
    for (int g = 0; g < 4; ++g) {
        i4 o;
        o.x = excl + loc[4 * g + 0]; o.y = excl + loc[4 * g + 1];
        o.z = excl + loc[4 * g + 2]; o.w = excl + loc[4 * g + 3];
        *(i4*)&offs[base + 4 * g] = o;
    }
    if (tid == 1023) offs[N] = excl + sum;
}

// ---- counting-sort edges into buckets; cursor atomic returns slot directly --
// 4 independent edge-chains per thread -> 4x memory-level parallelism on the
// c-load -> atomic -> store chain. rep = (e>>8)&7 matches k_degxw exactly.
// Cached (non-NT) record store: scattered 8B stores combine in L2 (NT was ~8x
// write amplification, measured round 3).
__global__ void k_bucket(const int* __restrict__ ei, const float* __restrict__ ew,
                         const float* __restrict__ dis, const int* __restrict__ offs,
                         int* __restrict__ cursor_rep, i2* __restrict__ barr,
                         int N, int E) {
    int t = blockIdx.x * blockDim.x + threadIdx.x;
    int qE = E >> 2;
    if (t >= qE) return;
    int e0 = t, e1 = t + qE, e2 = t + 2 * qE, e3 = t + 3 * qE;
    int r0 = ntload(ei + e0), c0 = ntload(ei + E + e0);
    int r1 = ntload(ei + e1), c1 = ntload(ei + E + e1);
    int r2 = ntload(ei + e2), c2 = ntload(ei + E + e2);
    int r3 = ntload(ei + e3), c3 = ntload(ei + E + e3);
    float n0 = dis[r0] * ntload(ew + e0) * dis[c0];
    float n1 = dis[r1] * ntload(ew + e1) * dis[c1];
    float n2 = dis[r2] * ntload(ew + e2) * dis[c2];
    float n3 = dis[r3] * ntload(ew + e3) * dis[c3];
    int p0 = offs[c0] + atomicAdd(&cursor_rep[(size_t)((e0 >> 8) & 7) * N + c0], 1);
    int p1 = offs[c1] + atomicAdd(&cursor_rep[(size_t)((e1 >> 8) & 7) * N + c1], 1);
    int p2 = offs[c2] + atomicAdd(&cursor_rep[(size_t)((e2 >> 8) & 7) * N + c2], 1);
    int p3 = offs[c3] + atomicAdd(&cursor_rep[(size_t)((e3 >> 8) & 7) * N + c3], 1);
    i2 x0; x0.x = r0; x0.y = __float_as_int(n0);
    i2 x1; x1.x = r1; x1.y = __float_as_int(n1);
    i2 x2; x2.x = r2; x2.y = __float_as_int(n2);
    i2 x3; x3.x = r3; x3.y = __float_as_int(n3);
    barr[p0] = x0;
    barr[p1] = x1;
    barr[p2] = x2;
    barr[p3] = x3;
}

// ---- FUSED gather + MLP + softmax ------------------------------------------
// 512 blocks x 8 waves: each wave handles 2 row pairs. The next pair's offs
// load issues right after the gather loop and its first chunk loads into the
// (dead) bcur register before the long MLP epilogue -> startup chain hidden.
// Chunk loads double-buffered; MLP layer 1 via wave-sync LDS broadcast.
// NOTE: no min-waves clamp (round 5's (512,4) forced VGPR<=64 -> 300MB spill).
__global__ __launch_bounds__(512) void k_gmlp(const int* __restrict__ offs,
                         const i2* __restrict__ barr,
                         const float* __restrict__ xw, const unsigned short* __restrict__ xw16,
                         const float* __restrict__ dis, const float* __restrict__ b1,
                         const float* __restrict__ Wm1, const float* __restrict__ bm1,
                         const float* __restrict__ Wm2, const float* __restrict__ bm2,
                         float* __restrict__ s, unsigned short* __restrict__ s16, int N) {
    __shared__ float w1m[4096], w2m[4096];   // 32 KB MLP weights
    __shared__ float hsc[8][2][64];          // 4 KB per-wave h rows (layer-1 bcast)
    __shared__ float tsc[8][2][64];          // 4 KB per-wave layer-1 outputs
    for (int t = threadIdx.x; t < 4096; t += 512) { w1m[t] = Wm1[t]; w2m[t] = Wm2[t]; }
    __syncthreads();
    int lane = threadIdx.x & 63;
    int sub = lane >> 4, q = lane & 15;
    int wv   = threadIdx.x >> 6;
    int NP   = N >> 1;
    int nw   = 8 * gridDim.x;
    int cp   = blockIdx.x * 8 + wv;
    if (cp >= NP) return;
    int c0 = 2 * cp, c1 = c0 + 1;
    int beg = ntload(offs + c0), mid = ntload(offs + c1), end = ntload(offs + c1 + 1);
    i2 bcur = (beg + lane < end) ? ntload(barr + beg + lane) : (i2){0, 0};
    const us4* xw16v = (const us4*)xw16;
    for (;;) {
        f4 A0 = {0.f, 0.f, 0.f, 0.f}, A1 = A0, B0 = A0, B1 = A0;
        int i = beg;
        while (i < end) {
            int inext = i + 64;
            i2 bnxt = {0, 0};
            if (inext + lane < end) bnxt = ntload(barr + inext + lane);   // prefetch
            int nloc = min(64, end - i);
            int   rv = bcur.x;
            float nv = __int_as_float(bcur.y);   // padded lanes: norm = 0
            int jmax = (nloc + 3) >> 2;
            int j = 0;
            for (; j + 4 <= jmax; j += 4) {   // 16 edges: 4 independent load chains
                int e0 = 4 * j + sub;
                int g0 = i + e0;
                int   r0 = __shfl(rv, e0),      r1 = __shfl(rv, e0 + 4);
                int   r2 = __shfl(rv, e0 + 8),  r3 = __shfl(rv, e0 + 12);
                float n0 = __shfl(nv, e0),      n1 = __shfl(nv, e0 + 4);
                float n2 = __shfl(nv, e0 + 8),  n3 = __shfl(nv, e0 + 12);
                us4 u0 = xw16v[(size_t)r0 * 16 + q];
                us4 u1 = xw16v[(size_t)r1 * 16 + q];
                us4 u2 = xw16v[(size_t)r2 * 16 + q];
                us4 u3 = xw16v[(size_t)r3 * 16 + q];
                float a0w = (g0      < mid) ? n0 : 0.f, b0w = n0 - a0w;
                float a1w = (g0 + 4  < mid) ? n1 : 0.f, b1w = n1 - a1w;
                float a2w = (g0 + 8  < mid) ? n2 : 0.f, b2w = n2 - a2w;
                float a3w = (g0 + 12 < mid) ? n3 : 0.f, b3w = n3 - a3w;
                A0.x = fmaf(bf2f(u0.x), a0w, A0.x); A0.y = fmaf(bf2f(u0.y), a0w, A0.y);
                A0.z = fmaf(bf2f(u0.z), a0w, A0.z); A0.w = fmaf(bf2f(u0.w), a0w, A0.w);
                B0.x = fmaf(bf2f(u0.x), b0w, B0.x); B0.y = fmaf(bf2f(u0.y), b0w, B0.y);
                B0.z = fmaf(bf2f(u0.z), b0w, B0.z); B0.w = fmaf(bf2f(u0.w), b0w, B0.w);
                A1.x = fmaf(bf2f(u1.x), a1w, A1.x); A1.y = fmaf(bf2f(u1.y), a1w, A1.y);
                A1.z = fmaf(bf2f(u1.z), a1w, A1.z); A1.w = fmaf(bf2f(u1.w), a1w, A1.w);
                B1.x = fmaf(bf2f(u1.x), b1w, B1.x); B1.y = fmaf(bf2f(u1.y), b1w, B1.y);
                B1.z = fmaf(bf2f(u1.z), b1w, B1.z); B1.w = fmaf(bf2f(u1.w), b1w, B1.w);
                A0.x = fmaf(bf2f(u2.x), a2w, A0.x); A0.y = fmaf(bf2f(u2.y), a2w, A0.y);
                A0.z = fmaf(bf2f(u2.z), a2w, A0.z); A0.w = fmaf(bf2f(u2.w), a2w, A0.w);
                B0.x = fmaf(bf2f(u2.x), b2w, B0.x); B0.y = fmaf(bf2f(u2.y), b2w, B0.y);
                B0.z = fmaf(bf2f(u2.z), b2w, B0.z); B0.w = fmaf(bf2f(u2.w), b2w, B0.w);
                A1.x = fmaf(bf2f(u3.x), a3w, A1.x); A1.y = fmaf(bf2f(u3.y), a3w, A1.y);
                A1.z = fmaf(bf2f(u3.z), a3w, A1.z); A1.w = fmaf(bf2f(u3.w), a3w, A1.w);
                B1.x = fmaf(bf2f(u3.x), b3w, B1.x); B1.y = fmaf(bf2f(u3.y), b3w, B1.y);
                B1.z = fmaf(bf2f(u3.z), b3w, B1.z); B1.w = fmaf(bf2f(u3.w), b3w, B1.w);
            }
            for (; j < jmax; ++j) {
                int e = 4 * j + sub;
                int g = i + e;
                int   r  = __shfl(rv, e);
                float nm = __shfl(nv, e);
                us4 u = xw16v[(size_t)r * 16 + q];
                float aw = (g < mid) ? nm : 0.f, bw = nm - aw;
                A0.x = fmaf(bf2f(u.x), aw, A0.x); A0.y = fmaf(bf2f(u.y), aw, A0.y);
                A0.z = fmaf(bf2f(u.z), aw, A0.z); A0.w = fmaf(bf2f(u.w), aw, A0.w);
                B0.x = fmaf(bf2f(u.x), bw, B0.x); B0.y = fmaf(bf2f(u.y), bw, B0.y);
                B0.z = fmaf(bf2f(u.z), bw, B0.z); B0.w = fmaf(bf2f(u.w), bw, B0.w);
            }
            i = inext;
            bcur = bnxt;
        }
        // ---- prefetch next pair's offs (latency hides under reduce+MLP) -----
        int cpn = cp + nw;
        int begN = 0, midN = 0, endN = 0;
        if (cpn < NP) {
            begN = ntload(offs + 2 * cpn);
            midN = ntload(offs + 2 * cpn + 1);
            endN = ntload(offs + 2 * cpn + 2);
        }
        A0.x += A1.x; A0.y += A1.y; A0.z += A1.z; A0.w += A1.w;
        B0.x += B1.x; B0.y += B1.y; B0.z += B1.z; B0.w += B1.w;
        A0.x += __shfl_xor(A0.x, 16); A0.y += __shfl_xor(A0.y, 16);
        A0.z += __shfl_xor(A0.z, 16); A0.w += __shfl_xor(A0.w, 16);
        B0.x += __shfl_xor(B0.x, 16); B0.y += __shfl_xor(B0.y, 16);
        B0.z += __shfl_xor(B0.z, 16); B0.w += __shfl_xor(B0.w, 16);
        A0.x += __shfl_xor(A0.x, 32); A0.y += __shfl_xor(A0.y, 32);
        A0.z += __shfl_xor(A0.z, 32); A0.w += __shfl_xor(A0.w, 32);
        B0.x += __shfl_xor(B0.x, 32); B0.y += __shfl_xor(B0.y, 32);
        B0.z += __shfl_xor(B0.z, 32); B0.w += __shfl_xor(B0.w, 32);
        // ---- issue next pair's first chunk into the dead bcur register ------
        if (cpn < NP) bcur = (begN + lane < endN) ? ntload(barr + begN + lane) : (i2){0, 0};
        // ---- epilogue for current pair --------------------------------------
        f4 bb = ((const f4*)b1)[q];
        f4 self0 = ntload((const f4*)xw + (size_t)c0 * 16 + q);
        f4 self1 = ntload((const f4*)xw + (size_t)c1 * 16 + q);
        float d0 = dis[c0], d1 = dis[c1];
        float dd0 = d0 * d0, dd1 = d1 * d1;
        f4 v0, v1;
        v0.x = A0.x + self0.x * dd0 + bb.x; v0.y = A0.y + self0.y * dd0 + bb.y;
        v0.z = A0.z + self0.z * dd0 + bb.z; v0.w = A0.w + self0.w * dd0 + bb.w;
        v1.x = B0.x + self1.x * dd1 + bb.x; v1.y = B0.y + self1.y * dd1 + bb.y;
        v1.z = B0.z + self1.z * dd1 + bb.z; v1.w = B0.w + self1.w * dd1 + bb.w;
        v0.x = v0.x > 0.f ? v0.x : 0.f; v0.y = v0.y > 0.f ? v0.y : 0.f;
        v0.z = v0.z > 0.f ? v0.z : 0.f; v0.w = v0.w > 0.f ? v0.w : 0.f;
        v1.x = v1.x > 0.f ? v1.x : 0.f; v1.y = v1.y > 0.f ? v1.y : 0.f;
        v1.z = v1.z > 0.f ? v1.z : 0.f; v1.w = v1.w > 0.f ? v1.w : 0.f;
        // ---- stage h rows to LDS (wave-sync broadcast) ----------------------
        if (sub == 0) {
            ((f4*)hsc[wv][0])[q] = v0;
            ((f4*)hsc[wv][1])[q] = v1;
        }
        // ---- MLP layer 1: t[l] = bm1[l] + sum_k h[k]*Wm1[k][l] --------------
        float t0 = bm1[lane], t1 = t0;
#pragma unroll
        for (int k = 0; k < 16; ++k) {
            f4 ha = ((f4*)hsc[wv][0])[k];
            f4 hb = ((f4*)hsc[wv][1])[k];
            float wa = w1m[(4 * k + 0) * 64 + lane];
            float wb = w1m[(4 * k + 1) * 64 + lane];
            float wc = w1m[(4 * k + 2) * 64 + lane];
            float wd = w1m[(4 * k + 3) * 64 + lane];
            t0 = fmaf(ha.x, wa, t0); t0 = fmaf(ha.y, wb, t0);
            t0 = fmaf(ha.z, wc, t0); t0 = fmaf(ha.w, wd, t0);
            t1 = fmaf(hb.x, wa, t1); t1 = fmaf(hb.y, wb, t1);
            t1 = fmaf(hb.z, wc, t1); t1 = fmaf(hb.w, wd, t1);
        }
        // ---- layer 2 via per-wave LDS scratch (broadcast reads) -------------
        tsc[wv][0][lane] = t0;
        tsc[wv][1][lane] = t1;
        float g0 = bm2[lane], g1 = g0;
#pragma unroll
        for (int k = 0; k < 16; ++k) {
            f4 ta = ((f4*)tsc[wv][0])[k];
            f4 tb = ((f4*)tsc[wv][1])[k];
            float wa = w2m[(4 * k + 0) * 64 + lane];
            float wb = w2m[(4 * k + 1) * 64 + lane];
            float wc = w2m[(4 * k + 2) * 64 + lane];
            float wd = w2m[(4 * k + 3) * 64 + lane];
            g0 = fmaf(ta.x, wa, g0); g0 = fmaf(ta.y, wb, g0);
            g0 = fmaf(ta.z, wc, g0); g0 = fmaf(ta.w, wd, g0);
            g1 = fmaf(tb.x, wa, g1); g1 = fmaf(tb.y, wb, g1);
            g1 = fmaf(tb.z, wc, g1); g1 = fmaf(tb.w, wd, g1);
        }
        // ---- softmax over the 64 lanes (one cluster dim per lane) -----------
        float m0 = g0, m1 = g1;
#pragma unroll
        for (int o = 32; o > 0; o >>= 1) {
            m0 = fmaxf(m0, __shfl_xor(m0, o));
            m1 = fmaxf(m1, __shfl_xor(m1, o));
        }
        float e0 = __expf(g0 - m0), e1 = __expf(g1 - m1);
        float z0 = e0, z1 = e1;
#pragma unroll
        for (int o = 32; o > 0; o >>= 1) {
            z0 += __shfl_xor(z0, o);
            z1 += __shfl_xor(z1, o);
        }
        float o0 = e0 / z0, o1 = e1 / z1;
        __builtin_nontemporal_store(o0, s + (size_t)c0 * 64 + lane);
        __builtin_nontemporal_store(o1, s + (size_t)c1 * 64 + lane);
        s16[(size_t)c0 * 64 + lane] = f2bf(o0);
        s16[(size_t)c1 * 64 + lane] = f2bf(o1);
        if (cpn >= NP) break;
        cp = cpn; c0 = 2 * cp; c1 = c0 + 1;
        beg = begN; mid = midN; end = endN;
    }
}

// ---- FAT kernel B: blocks [0,1024): trace (2 pairs/wave, prefetched);
// [1024,1280): row reductions ------------------------------------------------
__global__ __launch_bounds__(256) void k_rt(const int* __restrict__ offs,
                         const i2* __restrict__ barr,
                         const unsigned short* __restrict__ s16,
                         const float* __restrict__ s, const int* __restrict__ cnt,
                         float* __restrict__ ssg, float* __restrict__ cag,
                         float* __restrict__ csg, float* __restrict__ tracearr, int N) {
    __shared__ float tile[64][64];   // 16 KB (rowred branch)
    __shared__ float bsum;
    int lane = threadIdx.x & 63;
    int wv   = threadIdx.x >> 6;
    if (blockIdx.x >= 1024) {
        // ---- rowred branch: 256 blocks, one 64-row tile each ----
        int base = (blockIdx.x - 1024) * 64;
        if (base >= N) return;
        for (int t = threadIdx.x; t < 1024; t += 256)
            ((f4*)tile)[t] = ntload((const f4*)(s + (size_t)base * 64) + t);
        __syncthreads();
        float acc[16];
#pragma unroll
        for (int i = 0; i < 16; ++i) acc[i] = 0.f;
        for (int r = 0; r < 64; ++r) {
            float sj = tile[r][lane];
            const float* brow = &tile[r][wv * 16];
#pragma unroll
            for (int i = 0; i < 16; ++i) acc[i] = fmaf(brow[i], sj, acc[i]);
        }
        float csj = 0.f, caj = 0.f;
#pragma unroll
        for (int i = 0; i < 16; ++i) {
            int r = wv * 16 + i;
            float sj = tile[r][lane];
            csj += sj;
            caj = fmaf(sj, (float)cnt[base + r], caj);
        }
#pragma unroll
        for (int i = 0; i < 16; ++i) atomicAdd(&ssg[(wv * 16 + i) * 64 + lane], acc[i]);
        atomicAdd(&csg[lane], csj);
        atomicAdd(&cag[lane], caj);
        return;
    }
    // ---- trace branch: 1024 blocks, 2 pairs/wave, cross-pair prefetch -------
    int sub = lane >> 4, q = lane & 15;
    int NP = N >> 1;
    int nw = 4 * 1024;
    int cp = blockIdx.x * 4 + wv;
    const us4* s16v = (const us4*)s16;
    float tacc = 0.f;
    if (cp < NP) {
        int c0 = 2 * cp, c1 = c0 + 1;
        int beg = ntload(offs + c0), mid = ntload(offs + c1), end = ntload(offs + c1 + 1);
        us4 scu0 = s16v[(size_t)c0 * 16 + q];
        us4 scu1 = s16v[(size_t)c1 * 16 + q];
        int rcur = (beg + lane < end) ? ntload(barr + beg + lane).x : 0;
        for (;;) {
            f4 A0 = {0.f, 0.f, 0.f, 0.f}, A1 = A0, B0 = A0, B1 = A0;
            int i = beg;
            while (i < end) {
                int inext = i + 64;
                int rnxt = 0;
                if (inext + lane < end) rnxt = ntload(barr + inext + lane).x;   // prefetch
                int nloc = min(64, end - i);
                int rv = rcur;
                int jmax = (nloc + 3) >> 2;
                int j = 0;
                for (; j + 4 <= jmax; j += 4) {
                    int e0 = 4 * j + sub;
                    int g0 = i + e0;
                    int r0 = __shfl(rv, e0),     r1 = __shfl(rv, e0 + 4);
                    int r2 = __shfl(rv, e0 + 8), r3 = __shfl(rv, e0 + 12);
                    float n0 = (e0      < nloc) ? 1.f : 0.f;
                    float n1 = (e0 + 4  < nloc) ? 1.f : 0.f;
                    float n2 = (e0 + 8  < nloc) ? 1.f : 0.f;
                    float n3 = (e0 + 12 < nloc) ? 1.f : 0.f;
                    us4 u0 = s16v[(size_t)r0 * 16 + q];
                    us4 u1 = s16v[(size_t)r1 * 16 + q];
                    us4 u2 = s16v[(size_t)r2 * 16 + q];
                    us4 u3 = s16v[(size_t)r3 * 16 + q];
                    float a0w = (g0      < mid) ? n0 : 0.f, b0w = n0 - a0w;
                    float a1w = (g0 + 4  < mid) ? n1 : 0.f, b1w = n1 - a1w;
                    float a2w = (g0 + 8  < mid) ? n2 : 0.f, b2w = n2 - a2w;
                    float a3w = (g0 + 12 < mid) ? n3 : 0.f, b3w = n3 - a3w;
                    A0.x = fmaf(bf2f(u0.x), a0w, A0.x); A0.y = fmaf(bf2f(u0.y), a0w, A0.y);
                    A0.z = fmaf(bf2f(u0.z), a0w, A0.z); A0.w = fmaf(bf2f(u0.w), a0w, A0.w);
                    B0.x = fmaf(bf2f(u0.x), b0w, B0.x); B0.y = fmaf(bf2f(u0.y), b0w, B0.y);
                    B0.z = fmaf(bf2f(u0.z), b0w, B0.z); B0.w = fmaf(bf2f(u0.w), b0w, B0.w);
                    A1.x = fmaf(bf2f(u1.x), a1w, A1.x); A1.y = fmaf(bf2f(u1.y), a1w, A1.y);
                    A1.z = fmaf(bf2f(u1.z), a1w, A1.z); A1.w = fmaf(bf2f(u1.w), a1w, A1.w);
                    B1.x = fmaf(bf2f(u1.x), b1w, B1.x); B1.y = fmaf(bf2f(u1.y), b1w, B1.y);
                    B1.z = fmaf(bf2f(u1.z), b1w, B1.z); B1.w = fmaf(bf2f(u1.w), b1w, B1.w);
                    A0.x = fmaf(bf2f(u2.x), a2w, A0.x); A0.y = fmaf(bf2f(u2.y), a2w, A0.y);
                    A0.z = fmaf(bf2f(u2.z), a2w, A0.z); A0.w = fmaf(bf2f(u2.w), a2w, A0.w);
                    B0.x = fmaf(bf2f(u2.x), b2w, B0.x); B0.y = fmaf(bf2f(u2.y), b2w, B0.y);
                    B0.z = fmaf(bf2f(u2.z), b2w, B0.z); B0.w = fmaf(bf2f(u2.w), b2w, B0.w);
                    A1.x = fmaf(bf2f(u3.x), a3w, A1.x); A1.y = fmaf(bf2f(u3.y), a3w, A1.y);
                    A1.z = fmaf(bf2f(u3.z), a3w, A1.z); A1.w = fmaf(bf2f(u3.w), a3w, A1.w);
                    B1.x = fmaf(bf2f(u3.x), b3w, B1.x); B1.y = fmaf(bf2f(u3.y), b3w, B1.y);
                    B1.z = fmaf(bf2f(u3.z), b3w, B1.z); B1.w = fmaf(bf2f(u3.w), b3w, B1.w);
                }
                for (; j < jmax; ++j) {
                    int e = 4 * j + sub;
                    int g = i + e;
                    int r = __shfl(rv, e);
                    float m = (e < nloc) ? 1.f : 0.f;
                    us4 u = s16v[(size_t)r * 16 + q];
                    float aw = (g < mid) ? m : 0.f, bw = m - aw;
                    A0.x = fmaf(bf2f(u.x), aw, A0.x); A0.y = fmaf(bf2f(u.y), aw, A0.y);
                    A0.z = fmaf(bf2f(u.z), aw, A0.z); A0.w = fmaf(bf2f(u.w), aw, A0.w);
                    B0.x = fmaf(bf2f(u.x), bw, B0.x); B0.y = fmaf(bf2f(u.y), bw, B0.y);
                    B0.z = fmaf(bf2f(u.z), bw, B0.z); B0.w = fmaf(bf2f(u.w), bw, B0.w);
                }
                i = inext;
                rcur = rnxt;
            }
            // ---- prefetch next pair's offs (hides under reduction) ----------
            int cpn = cp + nw;
            int begN = 0, midN = 0, endN = 0;
            if (cpn < NP) {
                begN = ntload(offs + 2 * cpn);
                midN = ntload(offs + 2 * cpn + 1);
                endN = ntload(offs + 2 * cpn + 2);
            }
            A0.x += A1.x; A0.y += A1.y; A0.z += A1.z; A0.w += A1.w;
            B0.x += B1.x; B0.y += B1.y; B0.z += B1.z; B0.w += B1.w;
            A0.x += __shfl_xor(A0.x, 16); A0.y += __shfl_xor(A0.y, 16);
            A0.z += __shfl_xor(A0.z, 16); A0.w += __shfl_xor(A0.w, 16);
            B0.x += __shfl_xor(B0.x, 16); B0.y += __shfl_xor(B0.y, 16);
            B0.z += __shfl_xor(B0.z, 16); B0.w += __shfl_xor(B0.w, 16);
            A0.x += __shfl_xor(A0.x, 32); A0.y += __shfl_xor(A0.y, 32);
            A0.z += __shfl_xor(A0.z, 32); A0.w += __shfl_xor(A0.w, 32);
            B0.x += __shfl_xor(B0.x, 32); B0.y += __shfl_xor(B0.y, 32);
            B0.z += __shfl_xor(B0.z, 32); B0.w += __shfl_xor(B0.w, 32);
            // ---- issue next pair's scu rows + first chunk -------------------
            us4 scu0N = {0, 0, 0, 0}, scu1N = {0, 0, 0, 0};
            if (cpn < NP) {
                scu0N = s16v[(size_t)(2 * cpn) * 16 + q];
                scu1N = s16v[(size_t)(2 * cpn + 1) * 16 + q];
                rcur = (begN + lane < endN) ? ntload(barr + begN + lane).x : 0;
            }
            f4 sc0 = {bf2f(scu0.x), bf2f(scu0.y), bf2f(scu0.z), bf2f(scu0.w)};
            f4 sc1 = {bf2f(scu1.x), bf2f(scu1.y), bf2f(scu1.z), bf2f(scu1.w)};
            tacc += A0.x * sc0.x + A0.y * sc0.y + A0.z * sc0.z + A0.w * sc0.w;
            tacc += B0.x * sc1.x + B0.y * sc1.y + B0.z * sc1.z + B0.w * sc1.w;
            if (cpn >= NP) break;
            cp = cpn;
            beg = begN; mid = midN; end = endN;
            scu0 = scu0N; scu1 = scu1N;
        }
    }
    tacc *= 0.25f;   // each q-partial replicated across 4 subs
#pragma unroll
    for (int o = 32; o > 0; o >>= 1) tacc += __shfl_xor(tacc, o);
    if (threadIdx.x == 0) bsum = 0.f;
    __syncthreads();
    if (lane == 0) atomicAdd(&bsum, tacc);
    __syncthreads();
    if (threadIdx.x == 0) tracearr[blockIdx.x] = bsum;   // per-block partial
}

// ---- finalize: spectral + ortho + cluster loss ------------------------------
__global__ void k_final(const float* __restrict__ ssg, const float* __restrict__ cag,
                        const float* __restrict__ csg, const float* __restrict__ tracearr,
                        int ntr, float Ef, float Nf, float* __restrict__ out) {
    __shared__ float red[256];
    int tid = threadIdx.x;

    float a = 0.f;
    for (int t = tid; t < ntr; t += 256) a += tracearr[t];
    red[tid] = a; __syncthreads();
    for (int o = 128; o > 0; o >>= 1) { if (tid < o) red[tid] += red[tid + o]; __syncthreads(); }
    float trace = red[0]; __syncthreads();

    a = 0.f;
    for (int t = tid; t < 4096; t += 256) { float v = ssg[t]; a += v * v; }
    red[tid] = a; __syncthreads();
    for (int o = 128; o > 0; o >>= 1) { if (tid < o) red[tid] += red[tid + o]; __syncthreads(); }
    float ss_sumsq = red[0]; __syncthreads();

    a = (tid < 64) ? ssg[tid * 64 + tid] : 0.f;
    red[tid] = a; __syncthreads();
    for (int o = 128; o > 0; o >>= 1) { if (tid < o) red[tid] += red[tid + o]; __syncthreads(); }
    float tr_ss = red[0]; __syncthreads();

    a = (tid < 64) ? cag[tid] * cag[tid] : 0.f;
    red[tid] = a; __syncthreads();
    for (int o = 128; o > 0; o >>= 1) { if (tid < o) red[tid] += red[tid + o]; __syncthreads(); }
    float ca_ss = red[0]; __syncthreads();

    a = (tid < 64) ? csg[tid] * csg[tid] : 0.f;
    red[tid] = a; __syncthreads();
    for (int o = 128; o > 0; o >>= 1) { if (tid < o) red[tid] += red[tid + o]; __syncthreads(); }
    float cs_ss = red[0];

    if (tid == 0) {
        // 2m = deg.sum() = E
        float spec = -(trace - ca_ss / Ef) / Ef;
        float ss_fro = sqrtf(ss_sumsq);
        float ortho = sqrtf(fmaxf(2.f - tr_ss / (4.f * ss_fro), 0.f));
        float clus = sqrtf(cs_ss) / Nf * 8.f - 1.f;
        out[0] = spec + ortho + clus;
    }
}

extern "C" void kernel_launch(void* const* d_in, const int* in_sizes, int n_in,
                              void* d_out, int out_size, void* d_ws, size_t ws_size,
                              hipStream_t stream) {
    const float* x   = (const float*)d_in[0];
    const int*   ei  = (const int*)d_in[1];
    const float* ew  = (const float*)d_in[2];
    const float* W1  = (const float*)d_in[3];
    const float* b1  = (const float*)d_in[4];
    const float* Wm1 = (const float*)d_in[5];
    const float* bm1 = (const float*)d_in[6];
    const float* Wm2 = (const float*)d_in[7];
    const float* bm2 = (const float*)d_in[8];

    const int N = in_sizes[0] / 128;   // 16384
    const int E = in_sizes[2];         // 524288
    const int TGRID = 1280;            // fat kernel B grid (1024 trace + 256 rowred)

    char* base = (char*)d_ws;
    // --- zeroed region: deg_rep only (ssg/cag/csg zeroed by k_redscan) ---
    unsigned* deg_rep = (unsigned*)base;                            // 8N u32 (512 KB)
    size_t zbytes = (size_t)32 * N;
    // --- rest (cursor_rep fully written by k_redscan) ---
    char* up = base + zbytes;
    float* ssg = (float*)up;          up += (size_t)4 * (4096 + 128);  // ssg|cag|csg
    float* cag = ssg + 4096;
    float* csg = cag + 64;
    int*   cursor_rep = (int*)up;     up += (size_t)32 * N;         // 512 KB
    int*   cnt = (int*)up;            up += (size_t)4 * N;
    float* dis = (float*)up;          up += (size_t)4 * N;
    int*   offs = (int*)up;           up += (size_t)4 * (N + 1);
    float* tracearr = (float*)up;     up += (size_t)4 * 1024;
    up = (char*)(((size_t)up + 15) & ~(size_t)15);
    float* xw = (float*)up;           up += (size_t)4 * N * 64;     // 4 MB
    i2*    barr = (i2*)up;            up += (size_t)8 * E;          // 4 MB
    unsigned short* xw16 = (unsigned short*)up; up += (size_t)2 * N * 64;  // 2 MB
    unsigned short* s16  = (unsigned short*)up;                            // 2 MB
    float* sbuf = (float*)d_out;      // s lives in d_out (f32 output 0)

    hipMemsetAsync(d_ws, 0, zbytes, stream);

    k_degxw<<<1536, 256, 0, stream>>>(ei, ew, deg_rep, x, W1, xw, xw16, N, E);
    k_redscan<<<1, 1024, 0, stream>>>(deg_rep, cursor_rep, cnt, dis, offs, ssg, N);
    k_bucket<<<(E / 4 + 255) / 256, 256, 0, stream>>>(ei, ew, dis, offs, cursor_rep, barr, N, E);
    k_gmlp<<<512, 512, 0, stream>>>(offs, barr, xw, xw16, dis, b1, Wm1, bm1, Wm2, bm2, sbuf, s16, N);
    k_rt<<<TGRID, 256, 0, stream>>>(offs, barr, s16, sbuf, cnt, ssg, cag, csg, tracearr, N);
    k_final<<<1, 256, 0, stream>>>(ssg, cag, csg, tracearr, 1024, (float)E, (float)N,
                                   ((float*)d_out) + (size_t)N * 64);
}

// Round 11
// 213.921 us; speedup vs baseline: 1.1410x; 1.1410x over previous
//
#include <hip/hip_runtime.h>
#include <hip/hip_bf16.h>

typedef float          f4  __attribute__((ext_vector_type(4)));
typedef unsigned short us4 __attribute__((ext_vector_type(4)));
typedef int            i2  __attribute__((ext_vector_type(2)));

template <typename T>
__device__ __forceinline__ T ntload(const T* p) { return __builtin_nontemporal_load(p); }

__device__ __forceinline__ unsigned short f2bf(float f) {
    unsigned u = __float_as_uint(f);
    return (unsigned short)((u + 0x7FFF + ((u >> 16) & 1)) >> 16);   // RNE
}
__device__ __forceinline__ float bf2f(unsigned short h) {
    return __uint_as_float((unsigned)h << 16);
}

// ---- FAT kernel A: blocks [0,2048): degree histogram; [2048,2560): xw GEMM --
// deg: packed u32 = (count << 25) | fixed19(weight-sum); replica = (e>>8)&7
__global__ __launch_bounds__(256) void k_degxw(const int* __restrict__ ei,
                      const float* __restrict__ ew,
                      unsigned* __restrict__ deg_rep,
                      const float* __restrict__ x, const float* __restrict__ W1,
                      float* __restrict__ xw, unsigned short* __restrict__ xw16,
                      int N, int E) {
    __shared__ float w1l[128 * 64];   // 32 KB (xw branch)
    __shared__ f4    xt[16][32];      // 8 KB
    if (blockIdx.x < 2048) {
        int e = blockIdx.x * 256 + threadIdx.x;
        if (e < E) {
            int c = ntload(ei + E + e);
            float w = ntload(ew + e);
            unsigned q = __float2uint_rn(w * 524288.f);   // 2^19 fixed point
            atomicAdd(&deg_rep[(size_t)((e >> 8) & 7) * N + c], (1u << 25) | q);
        }
        return;
    }
    int xbid = blockIdx.x - 2048;     // 512 xw blocks
    for (int t = threadIdx.x; t < 128 * 64; t += 256) w1l[t] = W1[t];
    int lane = threadIdx.x & 63;
    int wv   = threadIdx.x >> 6;
    for (int base = xbid * 16; base < N; base += 512 * 16) {
        __syncthreads();   // also covers w1l staging on first pass
        for (int t = threadIdx.x; t < 16 * 32; t += 256)
            ((f4*)xt)[t] = ntload((const f4*)x + (size_t)base * 32 + t);
        __syncthreads();
        int r0 = wv * 4;
        float a0 = 0.f, a1 = 0.f, a2 = 0.f, a3 = 0.f;
#pragma unroll
        for (int q = 0; q < 32; ++q) {
            f4 x0 = xt[r0][q], x1 = xt[r0 + 1][q], x2 = xt[r0 + 2][q], x3 = xt[r0 + 3][q];
            float wa = w1l[(4 * q + 0) * 64 + lane];
            float wb = w1l[(4 * q + 1) * 64 + lane];
            float wc = w1l[(4 * q + 2) * 64 + lane];
            float wd = w1l[(4 * q + 3) * 64 + lane];
            a0 = fmaf(x0.x, wa, a0); a0 = fmaf(x0.y, wb, a0); a0 = fmaf(x0.z, wc, a0); a0 = fmaf(x0.w, wd, a0);
            a1 = fmaf(x1.x, wa, a1); a1 = fmaf(x1.y, wb, a1); a1 = fmaf(x1.z, wc, a1); a1 = fmaf(x1.w, wd, a1);
            a2 = fmaf(x2.x, wa, a2); a2 = fmaf(x2.y, wb, a2); a2 = fmaf(x2.z, wc, a2); a2 = fmaf(x2.w, wd, a2);
            a3 = fmaf(x3.x, wa, a3); a3 = fmaf(x3.y, wb, a3); a3 = fmaf(x3.z, wc, a3); a3 = fmaf(x3.w, wd, a3);
        }
        int gr = base + r0;
        __builtin_nontemporal_store(a0, xw + (size_t)(gr + 0) * 64 + lane);
        __builtin_nontemporal_store(a1, xw + (size_t)(gr + 1) * 64 + lane);
        __builtin_nontemporal_store(a2, xw + (size_t)(gr + 2) * 64 + lane);
        __builtin_nontemporal_store(a3, xw + (size_t)(gr + 3) * 64 + lane);
        xw16[(size_t)(gr + 0) * 64 + lane] = f2bf(a0);
        xw16[(size_t)(gr + 1) * 64 + lane] = f2bf(a1);
        xw16[(size_t)(gr + 2) * 64 + lane] = f2bf(a2);
        xw16[(size_t)(gr + 3) * 64 + lane] = f2bf(a3);
    }
}

// ---- reduce replicas: cnt[c], dis[c]=rsqrt(deg+1); cursor_rep pre-seeded ----
// cursor_rep[rep][c] is initialized to the per-rep running base, so k_bucket's
// atomicAdd RETURNS base+arrival directly (off_rep array + its gather deleted).
__global__ void k_red(const unsigned* __restrict__ deg_rep,
                      int* __restrict__ cursor_rep, int* __restrict__ cnt,
                      float* __restrict__ dis, int N) {
    int c = blockIdx.x * blockDim.x + threadIdx.x;
    if (c >= N) return;
    int run = 0;
    unsigned wsum = 0;
#pragma unroll
    for (int rep = 0; rep < 8; ++rep) {
        unsigned p = deg_rep[(size_t)rep * N + c];
        cursor_rep[(size_t)rep * N + c] = run;
        run += (int)(p >> 25);
        wsum += (p & ((1u << 25) - 1));
    }
    cnt[c] = run;
    dis[c] = rsqrtf((float)wsum * (1.f / 524288.f) + 1.0f);
}

// ---- exclusive prefix sum of cnt -> offs[0..N] (wave-scan, 2 barriers) ------
__global__ void k_scan(const int* __restrict__ cnt, int* __restrict__ offs, int N) {
    __shared__ int wsum[16];
    int tid = threadIdx.x;          // 1024 threads = 16 waves; N = 16384, C = 16
    int lane = tid & 63, wv = tid >> 6;
    int base = tid * 16;
    int loc[16];
    int sum = 0;
#pragma unroll
    for (int i = 0; i < 16; ++i) { loc[i] = sum; sum += cnt[base + i]; }
    int s = sum;                    // inclusive scan over 64 lanes
#pragma unroll
    for (int o = 1; o < 64; o <<= 1) {
        int t = __shfl_up(s, o);
        if (lane >= o) s += t;
    }
    if (lane == 63) wsum[wv] = s;
    __syncthreads();
    if (wv == 0 && lane < 16) {     // scan the 16 wave totals
        int ws = wsum[lane];
        int ss = ws;
#pragma unroll
        for (int o = 1; o < 16; o <<= 1) {
            int t = __shfl_up(ss, o);
            if (lane >= o) ss += t;
        }
        wsum[lane] = ss - ws;       // exclusive prefix of wave sums
    }
    __syncthreads();
    int excl = s - sum + wsum[wv];
#pragma unroll
    for (int i = 0; i < 16; ++i) offs[base + i] = excl + loc[i];
    if (tid == 1023) offs[N] = excl + sum;
}

// ---- counting-sort edges into buckets; cursor atomic returns slot directly --
// 2 independent edge-chains per thread (e and e+E/2) -> 2x memory-level
// parallelism on the c-load -> atomic -> store chain. rep = (e>>8)&7 matches
// k_degxw's histogram mapping exactly (bucket bases stay consistent).
// Cached (non-NT) record store: scattered 8B stores combine in L2 (NT was ~8x
// write amplification, measured round 3).
__global__ void k_bucket(const int* __restrict__ ei, const float* __restrict__ ew,
                         const float* __restrict__ dis, const int* __restrict__ offs,
                         int* __restrict__ cursor_rep, i2* __restrict__ barr,
                         int N, int E) {
    int t = blockIdx.x * blockDim.x + threadIdx.x;
    int h = E >> 1;
    if (t < h) {
        int e0 = t, e1 = t + h;
        int r0 = ntload(ei + e0), c0 = ntload(ei + E + e0);
        int r1 = ntload(ei + e1), c1 = ntload(ei + E + e1);
        float w0 = ntload(ew + e0), w1 = ntload(ew + e1);
        float n0 = dis[r0] * w0 * dis[c0];
        float n1 = dis[r1] * w1 * dis[c1];
        int rep0 = (e0 >> 8) & 7, rep1 = (e1 >> 8) & 7;
        int p0 = offs[c0] + atomicAdd(&cursor_rep[(size_t)rep0 * N + c0], 1);
        int p1 = offs[c1] + atomicAdd(&cursor_rep[(size_t)rep1 * N + c1], 1);
        i2 x0; x0.x = r0; x0.y = __float_as_int(n0);
        i2 x1; x1.x = r1; x1.y = __float_as_int(n1);
        barr[p0] = x0;
        barr[p1] = x1;
    }
}

// ---- FUSED gather + MLP + softmax ------------------------------------------
// 512 blocks x 8 waves: each wave handles 2 row pairs. The next pair's offs
// load issues right after the gather loop and its first chunk loads into the
// (dead) bcur register before the long MLP epilogue -> startup chain hidden.
// Chunk loads double-buffered; MLP layer 1 via wave-sync LDS broadcast.
// NOTE: no min-waves clamp (round 5's (512,4) forced VGPR<=64 -> 300MB spill).
__global__ __launch_bounds__(512) void k_gmlp(const int* __restrict__ offs,
                         const i2* __restrict__ barr,
                         const float* __restrict__ xw, const unsigned short* __restrict__ xw16,
                         const float* __restrict__ dis, const float* __restrict__ b1,
                         const float* __restrict__ Wm1, const float* __restrict__ bm1,
                         const float* __restrict__ Wm2, const float* __restrict__ bm2,
                         float* __restrict__ s, unsigned short* __restrict__ s16, int N) {
    __shared__ float w1m[4096], w2m[4096];   // 32 KB MLP weights
    __shared__ float hsc[8][2][64];          // 4 KB per-wave h rows (layer-1 bcast)
    __shared__ float tsc[8][2][64];          // 4 KB per-wave layer-1 outputs
    for (int t = threadIdx.x; t < 4096; t += 512) { w1m[t] = Wm1[t]; w2m[t] = Wm2[t]; }
    __syncthreads();
    int lane = threadIdx.x & 63;
    int sub = lane >> 4, q = lane & 15;
    int wv   = threadIdx.x >> 6;
    int NP   = N >> 1;
    int nw   = 8 * gridDim.x;
    int cp   = blockIdx.x * 8 + wv;
    if (cp >= NP) return;
    int c0 = 2 * cp, c1 = c0 + 1;
    int beg = ntload(offs + c0), mid = ntload(offs + c1), end = ntload(offs + c1 + 1);
    i2 bcur = (beg + lane < end) ? ntload(barr + beg + lane) : (i2){0, 0};
    const us4* xw16v = (const us4*)xw16;
    for (;;) {
        f4 A0 = {0.f, 0.f, 0.f, 0.f}, A1 = A0, B0 = A0, B1 = A0;
        int i = beg;
        while (i < end) {
            int inext = i + 64;
            i2 bnxt = {0, 0};
            if (inext + lane < end) bnxt = ntload(barr + inext + lane);   // prefetch
            int nloc = min(64, end - i);
            int   rv = bcur.x;
            float nv = __int_as_float(bcur.y);   // padded lanes: norm = 0
            int jmax = (nloc + 3) >> 2;
            int j = 0;
            for (; j + 4 <= jmax; j += 4) {   // 16 edges: 4 independent load chains
                int e0 = 4 * j + sub;
                int g0 = i + e0;
                int   r0 = __shfl(rv, e0),      r1 = __shfl(rv, e0 + 4);
                int   r2 = __shfl(rv, e0 + 8),  r3 = __shfl(rv, e0 + 12);
                float n0 = __shfl(nv, e0),      n1 = __shfl(nv, e0 + 4);
                float n2 = __shfl(nv, e0 + 8),  n3 = __shfl(nv, e0 + 12);
                us4 u0 = xw16v[(size_t)r0 * 16 + q];
                us4 u1 = xw16v[(size_t)r1 * 16 + q];
                us4 u2 = xw16v[(size_t)r2 * 16 + q];
                us4 u3 = xw16v[(size_t)r3 * 16 + q];
                float a0w = (g0      < mid) ? n0 : 0.f, b0w = n0 - a0w;
                float a1w = (g0 + 4  < mid) ? n1 : 0.f, b1w = n1 - a1w;
                float a2w = (g0 + 8  < mid) ? n2 : 0.f, b2w = n2 - a2w;
                float a3w = (g0 + 12 < mid) ? n3 : 0.f, b3w = n3 - a3w;
                A0.x = fmaf(bf2f(u0.x), a0w, A0.x); A0.y = fmaf(bf2f(u0.y), a0w, A0.y);
                A0.z = fmaf(bf2f(u0.z), a0w, A0.z); A0.w = fmaf(bf2f(u0.w), a0w, A0.w);
                B0.x = fmaf(bf2f(u0.x), b0w, B0.x); B0.y = fmaf(bf2f(u0.y), b0w, B0.y);
                B0.z = fmaf(bf2f(u0.z), b0w, B0.z); B0.w = fmaf(bf2f(u0.w), b0w, B0.w);
                A1.x = fmaf(bf2f(u1.x), a1w, A1.x); A1.y = fmaf(bf2f(u1.y), a1w, A1.y);
                A1.z = fmaf(bf2f(u1.z), a1w, A1.z); A1.w = fmaf(bf2f(u1.w), a1w, A1.w);
                B1.x = fmaf(bf2f(u1.x), b1w, B1.x); B1.y = fmaf(bf2f(u1.y), b1w, B1.y);
                B1.z = fmaf(bf2f(u1.z), b1w, B1.z); B1.w = fmaf(bf2f(u1.w), b1w, B1.w);
                A0.x = fmaf(bf2f(u2.x), a2w, A0.x); A0.y = fmaf(bf2f(u2.y), a2w, A0.y);
                A0.z = fmaf(bf2f(u2.z), a2w, A0.z); A0.w = fmaf(bf2f(u2.w), a2w, A0.w);
                B0.x = fmaf(bf2f(u2.x), b2w, B0.x); B0.y = fmaf(bf2f(u2.y), b2w, B0.y);
                B0.z = fmaf(bf2f(u2.z), b2w, B0.z); B0.w = fmaf(bf2f(u2.w), b2w, B0.w);
                A1.x = fmaf(bf2f(u3.x), a3w, A1.x); A1.y = fmaf(bf2f(u3.y), a3w, A1.y);
                A1.z = fmaf(bf2f(u3.z), a3w, A1.z); A1.w = fmaf(bf2f(u3.w), a3w, A1.w);
                B1.x = fmaf(bf2f(u3.x), b3w, B1.x); B1.y = fmaf(bf2f(u3.y), b3w, B1.y);
                B1.z = fmaf(bf2f(u3.z), b3w, B1.z); B1.w = fmaf(bf2f(u3.w), b3w, B1.w);
            }
            for (; j < jmax; ++j) {
                int e = 4 * j + sub;
                int g = i + e;
                int   r  = __shfl(rv, e);
                float nm = __shfl(nv, e);
                us4 u = xw16v[(size_t)r * 16 + q];
                float aw = (g < mid) ? nm : 0.f, bw = nm - aw;
                A0.x = fmaf(bf2f(u.x), aw, A0.x); A0.y = fmaf(bf2f(u.y), aw, A0.y);
                A0.z = fmaf(bf2f(u.z), aw, A0.z); A0.w = fmaf(bf2f(u.w), aw, A0.w);
                B0.x = fmaf(bf2f(u.x), bw, B0.x); B0.y = fmaf(bf2f(u.y), bw, B0.y);
                B0.z = fmaf(bf2f(u.z), bw, B0.z); B0.w = fmaf(bf2f(u.w), bw, B0.w);
            }
            i = inext;
            bcur = bnxt;
        }
        // ---- prefetch next pair's offs (latency hides under reduce+MLP) -----
        int cpn = cp + nw;
        int begN = 0, midN = 0, endN = 0;
        if (cpn < NP) {
            begN = ntload(offs + 2 * cpn);
            midN = ntload(offs + 2 * cpn + 1);
            endN = ntload(offs + 2 * cpn + 2);
        }
        A0.x += A1.x; A0.y += A1.y; A0.z += A1.z; A0.w += A1.w;
        B0.x += B1.x; B0.y += B1.y; B0.z += B1.z; B0.w += B1.w;
        A0.x += __shfl_xor(A0.x, 16); A0.y += __shfl_xor(A0.y, 16);
        A0.z += __shfl_xor(A0.z, 16); A0.w += __shfl_xor(A0.w, 16);
        B0.x += __shfl_xor(B0.x, 16); B0.y += __shfl_xor(B0.y, 16);
        B0.z += __shfl_xor(B0.z, 16); B0.w += __shfl_xor(B0.w, 16);
        A0.x += __shfl_xor(A0.x, 32); A0.y += __shfl_xor(A0.y, 32);
        A0.z += __shfl_xor(A0.z, 32); A0.w += __shfl_xor(A0.w, 32);
        B0.x += __shfl_xor(B0.x, 32); B0.y += __shfl_xor(B0.y, 32);
        B0.z += __shfl_xor(B0.z, 32); B0.w += __shfl_xor(B0.w, 32);
        // ---- issue next pair's first chunk into the dead bcur register ------
        if (cpn < NP) bcur = (begN + lane < endN) ? ntload(barr + begN + lane) : (i2){0, 0};
        // ---- epilogue for current pair --------------------------------------
        f4 bb = ((const f4*)b1)[q];
        f4 self0 = ntload((const f4*)xw + (size_t)c0 * 16 + q);
        f4 self1 = ntload((const f4*)xw + (size_t)c1 * 16 + q);
        float d0 = dis[c0], d1 = dis[c1];
        float dd0 = d0 * d0, dd1 = d1 * d1;
        f4 v0, v1;
        v0.x = A0.x + self0.x * dd0 + bb.x; v0.y = A0.y + self0.y * dd0 + bb.y;
        v0.z = A0.z + self0.z * dd0 + bb.z; v0.w = A0.w + self0.w * dd0 + bb.w;
        v1.x = B0.x + self1.x * dd1 + bb.x; v1.y = B0.y + self1.y * dd1 + bb.y;
        v1.z = B0.z + self1.z * dd1 + bb.z; v1.w = B0.w + self1.w * dd1 + bb.w;
        v0.x = v0.x > 0.f ? v0.x : 0.f; v0.y = v0.y > 0.f ? v0.y : 0.f;
        v0.z = v0.z > 0.f ? v0.z : 0.f; v0.w = v0.w > 0.f ? v0.w : 0.f;
        v1.x = v1.x > 0.f ? v1.x : 0.f; v1.y = v1.y > 0.f ? v1.y : 0.f;
        v1.z = v1.z > 0.f ? v1.z : 0.f; v1.w = v1.w > 0.f ? v1.w : 0.f;
        // ---- stage h rows to LDS (wave-sync broadcast) ----------------------
        if (sub == 0) {
            ((f4*)hsc[wv][0])[q] = v0;
            ((f4*)hsc[wv][1])[q] = v1;
        }
        // ---- MLP layer 1: t[l] = bm1[l] + sum_k h[k]*Wm1[k][l] --------------
        float t0 = bm1[lane], t1 = t0;
#pragma unroll
        for (int k = 0; k < 16; ++k) {
            f4 ha = ((f4*)hsc[wv][0])[k];
            f4 hb = ((f4*)hsc[wv][1])[k];
            float wa = w1m[(4 * k + 0) * 64 + lane];
            float wb = w1m[(4 * k + 1) * 64 + lane];
            float wc = w1m[(4 * k + 2) * 64 + lane];
            float wd = w1m[(4 * k + 3) * 64 + lane];
            t0 = fmaf(ha.x, wa, t0); t0 = fmaf(ha.y, wb, t0);
            t0 = fmaf(ha.z, wc, t0); t0 = fmaf(ha.w, wd, t0);
            t1 = fmaf(hb.x, wa, t1); t1 = fmaf(hb.y, wb, t1);
            t1 = fmaf(hb.z, wc, t1); t1 = fmaf(hb.w, wd, t1);
        }
        // ---- layer 2 via per-wave LDS scratch (broadcast reads) -------------
        tsc[wv][0][lane] = t0;
        tsc[wv][1][lane] = t1;
        float g0 = bm2[lane], g1 = g0;
#pragma unroll
        for (int k = 0; k < 16; ++k) {
            f4 ta = ((f4*)tsc[wv][0])[k];
            f4 tb = ((f4*)tsc[wv][1])[k];
            float wa = w2m[(4 * k + 0) * 64 + lane];
            float wb = w2m[(4 * k + 1) * 64 + lane];
            float wc = w2m[(4 * k + 2) * 64 + lane];
            float wd = w2m[(4 * k + 3) * 64 + lane];
            g0 = fmaf(ta.x, wa, g0); g0 = fmaf(ta.y, wb, g0);
            g0 = fmaf(ta.z, wc, g0); g0 = fmaf(ta.w, wd, g0);
            g1 = fmaf(tb.x, wa, g1); g1 = fmaf(tb.y, wb, g1);
            g1 = fmaf(tb.z, wc, g1); g1 = fmaf(tb.w, wd, g1);
        }
        // ---- softmax over the 64 lanes (one cluster dim per lane) -----------
        float m0 = g0, m1 = g1;
#pragma unroll
        for (int o = 32; o > 0; o >>= 1) {
            m0 = fmaxf(m0, __shfl_xor(m0, o));
            m1 = fmaxf(m1, __shfl_xor(m1, o));
        }
        float e0 = __expf(g0 - m0), e1 = __expf(g1 - m1);
        float z0 = e0, z1 = e1;
#pragma unroll
        for (int o = 32; o > 0; o >>= 1) {
            z0 += __shfl_xor(z0, o);
            z1 += __shfl_xor(z1, o);
        }
        float o0 = e0 / z0, o1 = e1 / z1;
        __builtin_nontemporal_store(o0, s + (size_t)c0 * 64 + lane);
        __builtin_nontemporal_store(o1, s + (size_t)c1 * 64 + lane);
        s16[(size_t)c0 * 64 + lane] = f2bf(o0);
        s16[(size_t)c1 * 64 + lane] = f2bf(o1);
        if (cpn >= NP) break;
        cp = cpn; c0 = 2 * cp; c1 = c0 + 1;
        beg = begN; mid = midN; end = endN;
    }
}

// ---- FAT kernel B: blocks [0,1024): trace (2 pairs/wave, prefetched);
// [1024,1280): row reductions ------------------------------------------------
__global__ __launch_bounds__(256) void k_rt(const int* __restrict__ offs,
                         const i2* __restrict__ barr,
                         const unsigned short* __restrict__ s16,
                         const float* __restrict__ s, const int* __restrict__ cnt,
                         float* __restrict__ ssg, float* __restrict__ cag,
                         float* __restrict__ csg, float* __restrict__ tracearr, int N) {
    __shared__ float tile[64][64];   // 16 KB (rowred branch)
    __shared__ float bsum;
    int lane = threadIdx.x & 63;
    int wv   = threadIdx.x >> 6;
    if (blockIdx.x >= 1024) {
        // ---- rowred branch: 256 blocks, one 64-row tile each ----
        int base = (blockIdx.x - 1024) * 64;
        if (base >= N) return;
        for (int t = threadIdx.x; t < 1024; t += 256)
            ((f4*)tile)[t] = ntload((const f4*)(s + (size_t)base * 64) + t);
        __syncthreads();
        float acc[16];
#pragma unroll
        for (int i = 0; i < 16; ++i) acc[i] = 0.f;
        for (int r = 0; r < 64; ++r) {
            float sj = tile[r][lane];
            const float* brow = &tile[r][wv * 16];
#pragma unroll
            for (int i = 0; i < 16; ++i) acc[i] = fmaf(brow[i], sj, acc[i]);
        }
        float csj = 0.f, caj = 0.f;
#pragma unroll
        for (int i = 0; i < 16; ++i) {
            int r = wv * 16 + i;
            float sj = tile[r][lane];
            csj += sj;
            caj = fmaf(sj, (float)cnt[base + r], caj);
        }
#pragma unroll
        for (int i = 0; i < 16; ++i) atomicAdd(&ssg[(wv * 16 + i) * 64 + lane], acc[i]);
        atomicAdd(&csg[lane], csj);
        atomicAdd(&cag[lane], caj);
        return;
    }
    // ---- trace branch: 1024 blocks, 2 pairs/wave, cross-pair prefetch -------
    int sub = lane >> 4, q = lane & 15;
    int NP = N >> 1;
    int nw = 4 * 1024;
    int cp = blockIdx.x * 4 + wv;
    const us4* s16v = (const us4*)s16;
    float tacc = 0.f;
    if (cp < NP) {
        int c0 = 2 * cp, c1 = c0 + 1;
        int beg = ntload(offs + c0), mid = ntload(offs + c1), end = ntload(offs + c1 + 1);
        us4 scu0 = s16v[(size_t)c0 * 16 + q];
        us4 scu1 = s16v[(size_t)c1 * 16 + q];
        int rcur = (beg + lane < end) ? ntload(barr + beg + lane).x : 0;
        for (;;) {
            f4 A0 = {0.f, 0.f, 0.f, 0.f}, A1 = A0, B0 = A0, B1 = A0;
            int i = beg;
            while (i < end) {
                int inext = i + 64;
                int rnxt = 0;
                if (inext + lane < end) rnxt = ntload(barr + inext + lane).x;   // prefetch
                int nloc = min(64, end - i);
                int rv = rcur;
                int jmax = (nloc + 3) >> 2;
                int j = 0;
                for (; j + 4 <= jmax; j += 4) {
                    int e0 = 4 * j + sub;
                    int g0 = i + e0;
                    int r0 = __shfl(rv, e0),     r1 = __shfl(rv, e0 + 4);
                    int r2 = __shfl(rv, e0 + 8), r3 = __shfl(rv, e0 + 12);
                    float n0 = (e0      < nloc) ? 1.f : 0.f;
                    float n1 = (e0 + 4  < nloc) ? 1.f : 0.f;
                    float n2 = (e0 + 8  < nloc) ? 1.f : 0.f;
                    float n3 = (e0 + 12 < nloc) ? 1.f : 0.f;
                    us4 u0 = s16v[(size_t)r0 * 16 + q];
                    us4 u1 = s16v[(size_t)r1 * 16 + q];
                    us4 u2 = s16v[(size_t)r2 * 16 + q];
                    us4 u3 = s16v[(size_t)r3 * 16 + q];
                    float a0w = (g0      < mid) ? n0 : 0.f, b0w = n0 - a0w;
                    float a1w = (g0 + 4  < mid) ? n1 : 0.f, b1w = n1 - a1w;
                    float a2w = (g0 + 8  < mid) ? n2 : 0.f, b2w = n2 - a2w;
                    float a3w = (g0 + 12 < mid) ? n3 : 0.f, b3w = n3 - a3w;
                    A0.x = fmaf(bf2f(u0.x), a0w, A0.x); A0.y = fmaf(bf2f(u0.y), a0w, A0.y);
                    A0.z = fmaf(bf2f(u0.z), a0w, A0.z); A0.w = fmaf(bf2f(u0.w), a0w, A0.w);
                    B0.x = fmaf(bf2f(u0.x), b0w, B0.x); B0.y = fmaf(bf2f(u0.y), b0w, B0.y);
                    B0.z = fmaf(bf2f(u0.z), b0w, B0.z); B0.w = fmaf(bf2f(u0.w), b0w, B0.w);
                    A1.x = fmaf(bf2f(u1.x), a1w, A1.x); A1.y = fmaf(bf2f(u1.y), a1w, A1.y);
                    A1.z = fmaf(bf2f(u1.z), a1w, A1.z); A1.w = fmaf(bf2f(u1.w), a1w, A1.w);
                    B1.x = fmaf(bf2f(u1.x), b1w, B1.x); B1.y = fmaf(bf2f(u1.y), b1w, B1.y);
                    B1.z = fmaf(bf2f(u1.z), b1w, B1.z); B1.w = fmaf(bf2f(u1.w), b1w, B1.w);
                    A0.x = fmaf(bf2f(u2.x), a2w, A0.x); A0.y = fmaf(bf2f(u2.y), a2w, A0.y);
                    A0.z = fmaf(bf2f(u2.z), a2w, A0.z); A0.w = fmaf(bf2f(u2.w), a2w, A0.w);
                    B0.x = fmaf(bf2f(u2.x), b2w, B0.x); B0.y = fmaf(bf2f(u2.y), b2w, B0.y);
                    B0.z = fmaf(bf2f(u2.z), b2w, B0.z); B0.w = fmaf(bf2f(u2.w), b2w, B0.w);
                    A1.x = fmaf(bf2f(u3.x), a3w, A1.x); A1.y = fmaf(bf2f(u3.y), a3w, A1.y);
                    A1.z = fmaf(bf2f(u3.z), a3w, A1.z); A1.w = fmaf(bf2f(u3.w), a3w, A1.w);
                    B1.x = fmaf(bf2f(u3.x), b3w, B1.x); B1.y = fmaf(bf2f(u3.y), b3w, B1.y);
                    B1.z = fmaf(bf2f(u3.z), b3w, B1.z); B1.w = fmaf(bf2f(u3.w), b3w, B1.w);
                }
                for (; j < jmax; ++j) {
                    int e = 4 * j + sub;
                    int g = i + e;
                    int r = __shfl(rv, e);
                    float m = (e < nloc) ? 1.f : 0.f;
                    us4 u = s16v[(size_t)r * 16 + q];
                    float aw = (g < mid) ? m : 0.f, bw = m - aw;
                    A0.x = fmaf(bf2f(u.x), aw, A0.x); A0.y = fmaf(bf2f(u.y), aw, A0.y);
                    A0.z = fmaf(bf2f(u.z), aw, A0.z); A0.w = fmaf(bf2f(u.w), aw, A0.w);
                    B0.x = fmaf(bf2f(u.x), bw, B0.x); B0.y = fmaf(bf2f(u.y), bw, B0.y);
                    B0.z = fmaf(bf2f(u.z), bw, B0.z); B0.w = fmaf(bf2f(u.w), bw, B0.w);
                }
                i = inext;
                rcur = rnxt;
            }
            // ---- prefetch next pair's offs (hides under reduction) ----------
            int cpn = cp + nw;
            int begN = 0, midN = 0, endN = 0;
            if (cpn < NP) {
                begN = ntload(offs + 2 * cpn);
                midN = ntload(offs + 2 * cpn + 1);
                endN = ntload(offs + 2 * cpn + 2);
            }
            A0.x += A1.x; A0.y += A1.y; A0.z += A1.z; A0.w += A1.w;
            B0.x += B1.x; B0.y += B1.y; B0.z += B1.z; B0.w += B1.w;
            A0.x += __shfl_xor(A0.x, 16); A0.y += __shfl_xor(A0.y, 16);
            A0.z += __shfl_xor(A0.z, 16); A0.w += __shfl_xor(A0.w, 16);
            B0.x += __shfl_xor(B0.x, 16); B0.y += __shfl_xor(B0.y, 16);
            B0.z += __shfl_xor(B0.z, 16); B0.w += __shfl_xor(B0.w, 16);
            A0.x += __shfl_xor(A0.x, 32); A0.y += __shfl_xor(A0.y, 32);
            A0.z += __shfl_xor(A0.z, 32); A0.w += __shfl_xor(A0.w, 32);
            B0.x += __shfl_xor(B0.x, 32); B0.y += __shfl_xor(B0.y, 32);
            B0.z += __shfl_xor(B0.z, 32); B0.w += __shfl_xor(B0.w, 32);
            // ---- issue next pair's scu rows + first chunk -------------------
            us4 scu0N = {0, 0, 0, 0}, scu1N = {0, 0, 0, 0};
            if (cpn < NP) {
                scu0N = s16v[(size_t)(2 * cpn) * 16 + q];
                scu1N = s16v[(size_t)(2 * cpn + 1) * 16 + q];
                rcur = (begN + lane < endN) ? ntload(barr + begN + lane).x : 0;
            }
            f4 sc0 = {bf2f(scu0.x), bf2f(scu0.y), bf2f(scu0.z), bf2f(scu0.w)};
            f4 sc1 = {bf2f(scu1.x), bf2f(scu1.y), bf2f(scu1.z), bf2f(scu1.w)};
            tacc += A0.x * sc0.x + A0.y * sc0.y + A0.z * sc0.z + A0.w * sc0.w;
            tacc += B0.x * sc1.x + B0.y * sc1.y + B0.z * sc1.z + B0.w * sc1.w;
            if (cpn >= NP) break;
            cp = cpn;
            beg = begN; mid = midN; end = endN;
            scu0 = scu0N; scu1 = scu1N;
        }
    }
    tacc *= 0.25f;   // each q-partial replicated across 4 subs
#pragma unroll
    for (int o = 32; o > 0; o >>= 1) tacc += __shfl_xor(tacc, o);
    if (threadIdx.x == 0) bsum = 0.f;
    __syncthreads();
    if (lane == 0) atomicAdd(&bsum, tacc);
    __syncthreads();
    if (threadIdx.x == 0) tracearr[blockIdx.x] = bsum;   // per-block partial
}

// ---- finalize: spectral + ortho + cluster loss ------------------------------
__global__ void k_final(const float* __restrict__ ssg, const float* __restrict__ cag,
                        const float* __restrict__ csg, const float* __restrict__ tracearr,
                        int ntr, float Ef, float Nf, float* __restrict__ out) {
    __shared__ float red[256];
    int tid = threadIdx.x;

    float a = 0.f;
    for (int t = tid; t < ntr; t += 256) a += tracearr[t];
    red[tid] = a; __syncthreads();
    for (int o = 128; o > 0; o >>= 1) { if (tid < o) red[tid] += red[tid + o]; __syncthreads(); }
    float trace = red[0]; __syncthreads();

    a = 0.f;
    for (int t = tid; t < 4096; t += 256) { float v = ssg[t]; a += v * v; }
    red[tid] = a; __syncthreads();
    for (int o = 128; o > 0; o >>= 1) { if (tid < o) red[tid] += red[tid + o]; __syncthreads(); }
    float ss_sumsq = red[0]; __syncthreads();

    a = (tid < 64) ? ssg[tid * 64 + tid] : 0.f;
    red[tid] = a; __syncthreads();
    for (int o = 128; o > 0; o >>= 1) { if (tid < o) red[tid] += red[tid + o]; __syncthreads(); }
    float tr_ss = red[0]; __syncthreads();

    a = (tid < 64) ? cag[tid] * cag[tid] : 0.f;
    red[tid] = a; __syncthreads();
    for (int o = 128; o > 0; o >>= 1) { if (tid < o) red[tid] += red[tid + o]; __syncthreads(); }
    float ca_ss = red[0]; __syncthreads();

    a = (tid < 64) ? csg[tid] * csg[tid] : 0.f;
    red[tid] = a; __syncthreads();
    for (int o = 128; o > 0; o >>= 1) { if (tid < o) red[tid] += red[tid + o]; __syncthreads(); }
    float cs_ss = red[0];

    if (tid == 0) {
        // 2m = deg.sum() = E
        float spec = -(trace - ca_ss / Ef) / Ef;
        float ss_fro = sqrtf(ss_sumsq);
        float ortho = sqrtf(fmaxf(2.f - tr_ss / (4.f * ss_fro), 0.f));
        float clus = sqrtf(cs_ss) / Nf * 8.f - 1.f;
        out[0] = spec + ortho + clus;
    }
}

extern "C" void kernel_launch(void* const* d_in, const int* in_sizes, int n_in,
                              void* d_out, int out_size, void* d_ws, size_t ws_size,
                              hipStream_t stream) {
    const float* x   = (const float*)d_in[0];
    const int*   ei  = (const int*)d_in[1];
    const float* ew  = (const float*)d_in[2];
    const float* W1  = (const float*)d_in[3];
    const float* b1  = (const float*)d_in[4];
    const float* Wm1 = (const float*)d_in[5];
    const float* bm1 = (const float*)d_in[6];
    const float* Wm2 = (const float*)d_in[7];
    const float* bm2 = (const float*)d_in[8];

    const int N = in_sizes[0] / 128;   // 16384
    const int E = in_sizes[2];         // 524288
    const int TGRID = 1280;            // fat kernel B grid (1024 trace + 256 rowred)

    char* base = (char*)d_ws;
    // --- zeroed region (atomics accumulate) ---
    unsigned* deg_rep = (unsigned*)base;                            // 8N u32 (512 KB)
    float* ssg = (float*)(base + (size_t)32 * N);                   // 4096 f
    float* cag = ssg + 4096;                                        // 64
    float* csg = cag + 64;                                          // 64
    size_t zbytes = (size_t)32 * N + (4096 + 128) * 4;
    // --- uninitialized region (cursor_rep fully written by k_red) ---
    char* up = base + ((zbytes + 15) & ~(size_t)15);
    int*   cursor_rep = (int*)up;     up += (size_t)32 * N;         // 512 KB
    int*   cnt = (int*)up;            up += (size_t)4 * N;
    float* dis = (float*)up;          up += (size_t)4 * N;
    int*   offs = (int*)up;           up += (size_t)4 * (N + 1);
    float* tracearr = (float*)up;     up += (size_t)4 * 1024;
    up = (char*)(((size_t)up + 15) & ~(size_t)15);
    float* xw = (float*)up;           up += (size_t)4 * N * 64;     // 4 MB
    i2*    barr = (i2*)up;            up += (size_t)8 * E;          // 4 MB
    unsigned short* xw16 = (unsigned short*)up; up += (size_t)2 * N * 64;  // 2 MB
    unsigned short* s16  = (unsigned short*)up;                            // 2 MB
    float* sbuf = (float*)d_out;      // s lives in d_out (f32 output 0)

    hipMemsetAsync(d_ws, 0, zbytes, stream);

    k_degxw<<<2560, 256, 0, stream>>>(ei, ew, deg_rep, x, W1, xw, xw16, N, E);
    k_red<<<(N + 255) / 256, 256, 0, stream>>>(deg_rep, cursor_rep, cnt, dis, N);
    k_scan<<<1, 1024, 0, stream>>>(cnt, offs, N);
    k_bucket<<<(E / 2 + 255) / 256, 256, 0, stream>>>(ei, ew, dis, offs, cursor_rep, barr, N, E);
    k_gmlp<<<512, 512, 0, stream>>>(offs, barr, xw, xw16, dis, b1, Wm1, bm1, Wm2, bm2, sbuf, s16, N);
    k_rt<<<TGRID, 256, 0, stream>>>(offs, barr, s16, sbuf, cnt, ssg, cag, csg, tracearr, N);
    k_final<<<1, 256, 0, stream>>>(ssg, cag, csg, tracearr, 1024, (float)E, (float)N,
                                   ((float*)d_out) + (size_t)N * 64);
}